// Round 6
// baseline (2370.694 us; speedup 1.0000x reference)
//
#include <hip/hip_runtime.h>
#include <hip/hip_cooperative_groups.h>
#include <math.h>

namespace cg = cooperative_groups;

#define N_NODES 100000
#define E_EDGES 3200000
#define IN_DIM_ 128
#define HID_ 64
#define BN_EPS_ 1e-5f

#define PB 200          // edge-chunk blocks
#define CHUNK 16000     // E / PB exactly
#define NBUCK 391       // ceil(N / 256): bucket = dst >> 8

#define CCH 6           // src chunks for locality sweep
#define CNODES 16667    // ceil(N / CCH)
#define CPS (N_NODES + 16)   // stride of cp arrays

#define GRID_CO 1280    // 5 blocks/CU guaranteed co-resident
#define NPW 20          // nodes per wave: 1280*4*20 = 102400 >= N

typedef __attribute__((ext_vector_type(8))) short short8;
typedef __attribute__((ext_vector_type(4))) float f32x4;

__device__ inline ushort f2bf(float f) {
    union { float f; unsigned u; } c; c.f = f;
    unsigned r = c.u + 0x7fff + ((c.u >> 16) & 1);   // RNE
    return (ushort)(r >> 16);
}
__device__ inline float bf2f(ushort s) {
    union { unsigned u; float f; } c; c.u = ((unsigned)s) << 16; return c.f;
}

// ---------------- pass A1: per-block bucket histogram ----------------
__global__ __launch_bounds__(256) void passA1_hist(const int* __restrict__ ei,
                                                   int* __restrict__ histPB) {
    __shared__ int hist[NBUCK];
    int t = threadIdx.x, b = blockIdx.x;
    for (int k = t; k < NBUCK; k += 256) hist[k] = 0;
    __syncthreads();
    int e0 = b * CHUNK, e1 = e0 + CHUNK;
    for (int e = e0 + t; e < e1; e += 256) {
        int d = ei[E_EDGES + e];
        atomicAdd(&hist[d >> 8], 1);
    }
    __syncthreads();
    for (int k = t; k < NBUCK; k += 256) histPB[k * PB + b] = hist[k];
}

// ---------------- per-bucket row scan ----------------
__global__ __launch_bounds__(256) void scan_rows(int* __restrict__ histPB,
                                                 int* __restrict__ bucket_tot) {
    __shared__ int wsum[4];
    int k = blockIdx.x, t = threadIdx.x, lane = t & 63, wv = t >> 6;
    int v = (t < PB) ? histPB[k * PB + t] : 0;
    int s = v;
#pragma unroll
    for (int off = 1; off < 64; off <<= 1) {
        int u = __shfl_up(s, off, 64);
        if (lane >= off) s += u;
    }
    if (lane == 63) wsum[wv] = s;
    __syncthreads();
    int wbase = 0;
    for (int w = 0; w < wv; w++) wbase += wsum[w];
    if (t < PB) histPB[k * PB + t] = wbase + s - v;
    if (t == 255) bucket_tot[k] = wbase + s;
}

// ---------------- scan bucket totals -> bucket_base ----------------
__global__ __launch_bounds__(512) void scan_totals(const int* __restrict__ bucket_tot,
                                                   int* __restrict__ bucket_base,
                                                   int* __restrict__ cp0) {
    __shared__ int wsum[8];
    int t = threadIdx.x, lane = t & 63, wv = t >> 6;
    int v = (t < NBUCK) ? bucket_tot[t] : 0;
    int s = v;
#pragma unroll
    for (int off = 1; off < 64; off <<= 1) {
        int u = __shfl_up(s, off, 64);
        if (lane >= off) s += u;
    }
    if (lane == 63) wsum[wv] = s;
    __syncthreads();
    int wbase = 0;
    for (int w = 0; w < wv; w++) wbase += wsum[w];
    if (t < NBUCK) bucket_base[t] = wbase + s - v;
    if (t == 0) {
        bucket_base[NBUCK] = E_EDGES;
        cp0[N_NODES] = E_EDGES;
    }
}

// ---------------- pass A2: bucket-scatter packed edges ----------------
__global__ __launch_bounds__(256) void passA2_scatter(const int* __restrict__ ei,
                                                      const int* __restrict__ histPB,
                                                      const int* __restrict__ bucket_base,
                                                      int* __restrict__ ebuf) {
    __shared__ int cur[NBUCK];
    int t = threadIdx.x, b = blockIdx.x;
    for (int k = t; k < NBUCK; k += 256) cur[k] = bucket_base[k] + histPB[k * PB + b];
    __syncthreads();
    int e0 = b * CHUNK, e1 = e0 + CHUNK;
    for (int e = e0 + t; e < e1; e += 256) {
        int s = ei[e];
        int d = ei[E_EDGES + e];
        int bk = d >> 8;
        int pos = atomicAdd(&cur[bk], 1);
        ebuf[pos] = s | ((d & 255) << 17);
    }
}

// ---- pass B: per-bucket place, chunk-grouped within node; emits cp + dinv ----
__global__ __launch_bounds__(256) void passB_place(const int* __restrict__ ebuf,
                                                   const int* __restrict__ bucket_base,
                                                   int* __restrict__ csr_src,
                                                   float* __restrict__ dinv,
                                                   int* __restrict__ cp) {
    __shared__ int hist[256 * CCH];
    __shared__ int wsum[4];
    int b = blockIdx.x, t = threadIdx.x, lane = t & 63, wv = t >> 6;
    int base = bucket_base[b], end = bucket_base[b + 1];
    for (int k = t; k < 256 * CCH; k += 256) hist[k] = 0;
    __syncthreads();
    for (int k = base + t; k < end; k += 256) {
        int pv = ebuf[k];
        int node = (pv >> 17) & 255;
        unsigned src = pv & 0x1FFFF;
        int c = src / CNODES;
        atomicAdd(&hist[node * CCH + c], 1);
    }
    __syncthreads();
    int v[CCH];
    int tot = 0;
#pragma unroll
    for (int c = 0; c < CCH; c++) { v[c] = hist[t * CCH + c]; tot += v[c]; }
    int s = tot;
#pragma unroll
    for (int off = 1; off < 64; off <<= 1) {
        int u = __shfl_up(s, off, 64);
        if (lane >= off) s += u;
    }
    if (lane == 63) wsum[wv] = s;
    __syncthreads();
    int wbase = 0;
    for (int w = 0; w < wv; w++) wbase += wsum[w];
    int excl = wbase + s - tot;          // node's exclusive start within bucket
    int node = b * 256 + t;
    if (node < N_NODES) dinv[node] = rsqrtf((float)tot + 1.0f);
    int run = excl;
#pragma unroll
    for (int c = 0; c < CCH; c++) {
        if (node < N_NODES) cp[c * CPS + node] = base + run;
        hist[t * CCH + c] = run;         // bucket-relative cursor
        run += v[c];
    }
    __syncthreads();
    for (int k = base + t; k < end; k += 256) {
        int pv = ebuf[k];
        int nd = (pv >> 17) & 255;
        unsigned src = pv & 0x1FFFF;
        int c = src / CNODES;
        int pos = atomicAdd(&hist[nd * CCH + c], 1);
        csr_src[base + pos] = (int)src;
    }
}

// ---------------- MFMA GEMM: hs(bf16) = (X @ W) * dinv[row] ----------------
template<int K, bool BF16IN>
__global__ __launch_bounds__(256) void gemm_bf16(const void* __restrict__ Xv,
                                                 const float* __restrict__ W,   // [K][64]
                                                 const float* __restrict__ dinv,
                                                 ushort* __restrict__ hs) {     // [N][64] bf16
    constexpr int KP = K + 8;
    __shared__ ushort A_lds[64][KP];
    __shared__ ushort Wt_lds[64][KP];
    int t = threadIdx.x;
    long row0 = (long)blockIdx.x * 64;

    for (int i = t; i < K * 16; i += 256) {
        float4 w4 = ((const float4*)W)[i];
        int k = i >> 4, n = (i & 15) * 4;
        Wt_lds[n + 0][k] = f2bf(w4.x);
        Wt_lds[n + 1][k] = f2bf(w4.y);
        Wt_lds[n + 2][k] = f2bf(w4.z);
        Wt_lds[n + 3][k] = f2bf(w4.w);
    }
    if (BF16IN) {
        constexpr int K2 = K / 2;
        const unsigned* X = (const unsigned*)Xv;
        for (int i = t; i < 64 * K2; i += 256) {
            int r = i / K2, c = i % K2;
            unsigned val = 0;
            long row = row0 + r;
            if (row < N_NODES) val = X[row * K2 + c];
            *(unsigned*)&A_lds[r][c * 2] = val;
        }
    } else {
        constexpr int K4 = K / 4;
        const float* X = (const float*)Xv;
        for (int i = t; i < 64 * K4; i += 256) {
            int r = i / K4, c = i % K4;
            float4 val = make_float4(0.f, 0.f, 0.f, 0.f);
            long row = row0 + r;
            if (row < N_NODES) val = ((const float4*)X)[row * K4 + c];
            int cb = c * 4;
            A_lds[r][cb + 0] = f2bf(val.x);
            A_lds[r][cb + 1] = f2bf(val.y);
            A_lds[r][cb + 2] = f2bf(val.z);
            A_lds[r][cb + 3] = f2bf(val.w);
        }
    }
    __syncthreads();

    int w = t >> 6, l = t & 63;
    int m = l & 15, quad = l >> 4;
    f32x4 acc[4];
#pragma unroll
    for (int c = 0; c < 4; c++) acc[c] = (f32x4){0.f, 0.f, 0.f, 0.f};

#pragma unroll
    for (int ch = 0; ch < K / 32; ch++) {
        short8 a = *(const short8*)&A_lds[16 * w + m][32 * ch + 8 * quad];
#pragma unroll
        for (int c = 0; c < 4; c++) {
            short8 b = *(const short8*)&Wt_lds[16 * c + m][32 * ch + 8 * quad];
            acc[c] = __builtin_amdgcn_mfma_f32_16x16x32_bf16(a, b, acc[c], 0, 0, 0);
        }
    }

#pragma unroll
    for (int r = 0; r < 4; r++) {
        long node = row0 + 16 * w + quad * 4 + r;
        if (node < N_NODES) {
            float dv = dinv[node];
#pragma unroll
            for (int c = 0; c < 4; c++)
                hs[node * 64 + 16 * c + m] = f2bf(acc[c][r] * dv);
        }
    }
}

// ------- cooperative chunk-sweep gather + fused BN/ReLU (+gemv3 if LAST) -------
// Persistent: wave owns NPW contiguous nodes, acc in VGPRs (lane = feature).
// Sweeps src chunks with grid.sync() between -> per-XCD L2 holds one 2.1 MB slice.
template<bool LAST>
__global__ __launch_bounds__(256, 5) void gather_coop(const int* __restrict__ csr_src,
                                                      const int* __restrict__ cp,
                                                      const ushort* __restrict__ hs,
                                                      const float* __restrict__ dinv,
                                                      const float* __restrict__ b,
                                                      const float* __restrict__ g,
                                                      const float* __restrict__ beta,
                                                      const float* __restrict__ m,
                                                      const float* __restrict__ v,
                                                      ushort* __restrict__ y,
                                                      const float* __restrict__ W3,
                                                      float* __restrict__ hs3) {
    cg::grid_group grid = cg::this_grid();
    int wave = blockIdx.x * 4 + (threadIdx.x >> 6);
    int j = threadIdx.x & 63;
    int i0 = wave * NPW;

    float acc[NPW];
#pragma unroll
    for (int nb = 0; nb < NPW; nb++) {
        int i = i0 + nb;
        acc[nb] = (i < N_NODES) ? bf2f(hs[(long)i * 64 + j]) : 0.f;  // self-loop
    }

#pragma unroll
    for (int c = 0; c < CCH; c++) {
        if (c) grid.sync();
#pragma unroll
        for (int nb = 0; nb < NPW; nb++) {
            int i = i0 + nb;
            if (i >= N_NODES) continue;
            int cs = cp[c * CPS + i];
            int ce = (c == CCH - 1) ? cp[i + 1] : cp[(c + 1) * CPS + i];
            float a = acc[nb];
            int k = cs;
            for (; k + 3 < ce; k += 4) {
                int s0 = csr_src[k], s1 = csr_src[k + 1];
                int s2 = csr_src[k + 2], s3 = csr_src[k + 3];
                float f0 = bf2f(hs[(long)s0 * 64 + j]);
                float f1 = bf2f(hs[(long)s1 * 64 + j]);
                float f2 = bf2f(hs[(long)s2 * 64 + j]);
                float f3 = bf2f(hs[(long)s3 * 64 + j]);
                a += (f0 + f1) + (f2 + f3);
            }
            for (; k < ce; k++) a += bf2f(hs[(long)csr_src[k] * 64 + j]);
            acc[nb] = a;
        }
    }

    // epilogue
    float bj = b[j], mj = m[j], bej = beta[j];
    float sc = g[j] * rsqrtf(v[j] + BN_EPS_);
    float w3 = LAST ? W3[j] : 0.f;
#pragma unroll
    for (int nb = 0; nb < NPW; nb++) {
        int i = i0 + nb;
        if (i >= N_NODES) break;
        float di = dinv[i];
        float o = fmaxf((di * acc[nb] + bj - mj) * sc + bej, 0.f);
        if (LAST) {
            float p = o * w3;
#pragma unroll
            for (int off = 32; off > 0; off >>= 1) p += __shfl_xor(p, off, 64);
            if (j == 0) hs3[i] = p * di;
        } else {
            y[(long)i * 64 + j] = f2bf(o);
        }
    }
}

// ---------------- layer-3 pull + sigmoid ----------------
__global__ __launch_bounds__(256) void gather3(const int* __restrict__ row_ptr,
                                               const int* __restrict__ csr_src,
                                               const float* __restrict__ hs3,
                                               const float* __restrict__ dinv,
                                               const float* __restrict__ b3,
                                               float* __restrict__ out, int n) {
    int i = blockIdx.x * 256 + threadIdx.x;
    if (i >= n) return;
    int beg = row_ptr[i], end = row_ptr[i + 1];
    float s0 = hs3[i], s1 = 0.f, s2 = 0.f, s3 = 0.f;
    float s4 = 0.f, s5 = 0.f, s6 = 0.f, s7 = 0.f;
    int k = beg;
    for (; k + 8 <= end; k += 8) {
        s0 += hs3[csr_src[k]];
        s1 += hs3[csr_src[k + 1]];
        s2 += hs3[csr_src[k + 2]];
        s3 += hs3[csr_src[k + 3]];
        s4 += hs3[csr_src[k + 4]];
        s5 += hs3[csr_src[k + 5]];
        s6 += hs3[csr_src[k + 6]];
        s7 += hs3[csr_src[k + 7]];
    }
    for (; k < end; k++) s0 += hs3[csr_src[k]];
    float z = dinv[i] * (((s0 + s1) + (s2 + s3)) + ((s4 + s5) + (s6 + s7))) + b3[0];
    out[i] = 1.f / (1.f + expf(-z));
}

extern "C" void kernel_launch(void* const* d_in, const int* in_sizes, int n_in,
                              void* d_out, int out_size, void* d_ws, size_t ws_size,
                              hipStream_t stream) {
    const int N = N_NODES;
    const int E = E_EDGES;

    const float* x   = (const float*)d_in[0];
    const int*   ei  = (const int*)d_in[1];   // [2, E]: row0=src, row1=dst
    const float* W1  = (const float*)d_in[2];
    const float* b1  = (const float*)d_in[3];
    const float* W2  = (const float*)d_in[4];
    const float* b2  = (const float*)d_in[5];
    const float* W3  = (const float*)d_in[6];
    const float* b3  = (const float*)d_in[7];
    const float* g1  = (const float*)d_in[8];
    const float* bt1 = (const float*)d_in[9];
    const float* m1  = (const float*)d_in[10];
    const float* v1  = (const float*)d_in[11];
    const float* g2  = (const float*)d_in[12];
    const float* bt2 = (const float*)d_in[13];
    const float* m2  = (const float*)d_in[14];
    const float* v2  = (const float*)d_in[15];
    float* out = (float*)d_out;

    // workspace layout (4-byte units)
    int*    wsi         = (int*)d_ws;
    float*  dinv        = (float*)wsi;                    // N
    float*  hs3         = (float*)(wsi + (long)N);        // N
    int*    cp          = wsi + 2L * N;                   // CCH*CPS (+cp0[N]=E)
    int*    histPB      = cp + (long)CCH * CPS;           // NBUCK*PB
    int*    bucket_tot  = histPB + NBUCK * PB;            // NBUCK (pad 400)
    int*    bucket_base = bucket_tot + 400;               // NBUCK+1 (pad 400)
    int*    csr_src     = bucket_base + 400;              // E
    ushort* hsb         = (ushort*)(csr_src + (long)E);   // N*64 bf16 = 32N ints
    ushort* yb          = (ushort*)(csr_src + (long)E + 32L * N); // N*64 bf16
    int*    ebuf        = (int*)hsb;                      // E ints, aliases hsb

    // ---- CSR build (bucketed counting sort; chunk-grouped rows) ----
    passA1_hist<<<PB, 256, 0, stream>>>(ei, histPB);
    scan_rows<<<NBUCK, 256, 0, stream>>>(histPB, bucket_tot);
    scan_totals<<<1, 512, 0, stream>>>(bucket_tot, bucket_base, cp);
    passA2_scatter<<<PB, 256, 0, stream>>>(ei, histPB, bucket_base, ebuf);
    passB_place<<<NBUCK, 256, 0, stream>>>(ebuf, bucket_base, csr_src, dinv, cp);

    // ---- layer 1 ----
    gemm_bf16<IN_DIM_, false><<<(N + 63) / 64, 256, 0, stream>>>(x, W1, dinv, hsb);
    {
        void* a1[] = {(void*)&csr_src, (void*)&cp, (void*)&hsb, (void*)&dinv,
                      (void*)&b1, (void*)&g1, (void*)&bt1, (void*)&m1, (void*)&v1,
                      (void*)&yb, (void*)&W3, (void*)&hs3};
        hipLaunchCooperativeKernel((const void*)gather_coop<false>, dim3(GRID_CO),
                                   dim3(256), a1, 0, stream);
    }
    // ---- layer 2 (+ fused gemv3) ----
    gemm_bf16<HID_, true><<<(N + 63) / 64, 256, 0, stream>>>(yb, W2, dinv, hsb);
    {
        void* a2[] = {(void*)&csr_src, (void*)&cp, (void*)&hsb, (void*)&dinv,
                      (void*)&b2, (void*)&g2, (void*)&bt2, (void*)&m2, (void*)&v2,
                      (void*)&yb, (void*)&W3, (void*)&hs3};
        hipLaunchCooperativeKernel((const void*)gather_coop<true>, dim3(GRID_CO),
                                   dim3(256), a2, 0, stream);
    }
    // ---- layer 3 ----
    gather3<<<(N + 255) / 256, 256, 0, stream>>>(cp, csr_src, hs3, dinv, b3, out, N);
}

// Round 7
// 852.326 us; speedup vs baseline: 2.7814x; 2.7814x over previous
//
#include <hip/hip_runtime.h>
#include <math.h>

#define N_NODES 100000
#define E_EDGES 3200000
#define IN_DIM_ 128
#define HID_ 64
#define BN_EPS_ 1e-5f

#define PB 200          // edge-chunk blocks
#define CHUNK 16000     // E / PB exactly
#define NBUCK 391       // ceil(N / 256): bucket = dst >> 8

#define CCH 6           // src chunks for locality sweep
#define CNODES 16667    // ceil(N / CCH)
#define CPS (N_NODES + 16)   // stride of cp arrays

#define NPW 16          // nodes per wave
#define GB 1563         // ceil(N / (4*NPW)) blocks -> all co-resident

typedef __attribute__((ext_vector_type(8))) short short8;
typedef __attribute__((ext_vector_type(4))) float f32x4;

__device__ inline ushort f2bf(float f) {
    union { float f; unsigned u; } c; c.f = f;
    unsigned r = c.u + 0x7fff + ((c.u >> 16) & 1);   // RNE
    return (ushort)(r >> 16);
}
__device__ inline float bf2f(ushort s) {
    union { unsigned u; float f; } c; c.u = ((unsigned)s) << 16; return c.f;
}

// ---------------- pass A1: per-block bucket histogram ----------------
__global__ __launch_bounds__(256) void passA1_hist(const int* __restrict__ ei,
                                                   int* __restrict__ histPB) {
    __shared__ int hist[NBUCK];
    int t = threadIdx.x, b = blockIdx.x;
    for (int k = t; k < NBUCK; k += 256) hist[k] = 0;
    __syncthreads();
    int e0 = b * CHUNK, e1 = e0 + CHUNK;
    for (int e = e0 + t; e < e1; e += 256) {
        int d = ei[E_EDGES + e];
        atomicAdd(&hist[d >> 8], 1);
    }
    __syncthreads();
    for (int k = t; k < NBUCK; k += 256) histPB[k * PB + b] = hist[k];
}

// ---------------- per-bucket row scan ----------------
__global__ __launch_bounds__(256) void scan_rows(int* __restrict__ histPB,
                                                 int* __restrict__ bucket_tot) {
    __shared__ int wsum[4];
    int k = blockIdx.x, t = threadIdx.x, lane = t & 63, wv = t >> 6;
    int v = (t < PB) ? histPB[k * PB + t] : 0;
    int s = v;
#pragma unroll
    for (int off = 1; off < 64; off <<= 1) {
        int u = __shfl_up(s, off, 64);
        if (lane >= off) s += u;
    }
    if (lane == 63) wsum[wv] = s;
    __syncthreads();
    int wbase = 0;
    for (int w = 0; w < wv; w++) wbase += wsum[w];
    if (t < PB) histPB[k * PB + t] = wbase + s - v;
    if (t == 255) bucket_tot[k] = wbase + s;
}

// ---------------- scan bucket totals -> bucket_base ----------------
__global__ __launch_bounds__(512) void scan_totals(const int* __restrict__ bucket_tot,
                                                   int* __restrict__ bucket_base,
                                                   int* __restrict__ cp0) {
    __shared__ int wsum[8];
    int t = threadIdx.x, lane = t & 63, wv = t >> 6;
    int v = (t < NBUCK) ? bucket_tot[t] : 0;
    int s = v;
#pragma unroll
    for (int off = 1; off < 64; off <<= 1) {
        int u = __shfl_up(s, off, 64);
        if (lane >= off) s += u;
    }
    if (lane == 63) wsum[wv] = s;
    __syncthreads();
    int wbase = 0;
    for (int w = 0; w < wv; w++) wbase += wsum[w];
    if (t < NBUCK) bucket_base[t] = wbase + s - v;
    if (t == 0) {
        bucket_base[NBUCK] = E_EDGES;
        cp0[N_NODES] = E_EDGES;
    }
}

// ---------------- pass A2: bucket-scatter packed edges ----------------
__global__ __launch_bounds__(256) void passA2_scatter(const int* __restrict__ ei,
                                                      const int* __restrict__ histPB,
                                                      const int* __restrict__ bucket_base,
                                                      int* __restrict__ ebuf) {
    __shared__ int cur[NBUCK];
    int t = threadIdx.x, b = blockIdx.x;
    for (int k = t; k < NBUCK; k += 256) cur[k] = bucket_base[k] + histPB[k * PB + b];
    __syncthreads();
    int e0 = b * CHUNK, e1 = e0 + CHUNK;
    for (int e = e0 + t; e < e1; e += 256) {
        int s = ei[e];
        int d = ei[E_EDGES + e];
        int bk = d >> 8;
        int pos = atomicAdd(&cur[bk], 1);
        ebuf[pos] = s | ((d & 255) << 17);
    }
}

// ---- pass B: per-bucket place, chunk-grouped within node; emits cp + dinv ----
__global__ __launch_bounds__(256) void passB_place(const int* __restrict__ ebuf,
                                                   const int* __restrict__ bucket_base,
                                                   int* __restrict__ csr_src,
                                                   float* __restrict__ dinv,
                                                   int* __restrict__ cp) {
    __shared__ int hist[256 * CCH];
    __shared__ int wsum[4];
    int b = blockIdx.x, t = threadIdx.x, lane = t & 63, wv = t >> 6;
    int base = bucket_base[b], end = bucket_base[b + 1];
    for (int k = t; k < 256 * CCH; k += 256) hist[k] = 0;
    __syncthreads();
    for (int k = base + t; k < end; k += 256) {
        int pv = ebuf[k];
        int node = (pv >> 17) & 255;
        unsigned src = pv & 0x1FFFF;
        int c = src / CNODES;
        atomicAdd(&hist[node * CCH + c], 1);
    }
    __syncthreads();
    int v[CCH];
    int tot = 0;
#pragma unroll
    for (int c = 0; c < CCH; c++) { v[c] = hist[t * CCH + c]; tot += v[c]; }
    int s = tot;
#pragma unroll
    for (int off = 1; off < 64; off <<= 1) {
        int u = __shfl_up(s, off, 64);
        if (lane >= off) s += u;
    }
    if (lane == 63) wsum[wv] = s;
    __syncthreads();
    int wbase = 0;
    for (int w = 0; w < wv; w++) wbase += wsum[w];
    int excl = wbase + s - tot;          // node's exclusive start within bucket
    int node = b * 256 + t;
    if (node < N_NODES) dinv[node] = rsqrtf((float)tot + 1.0f);
    int run = excl;
#pragma unroll
    for (int c = 0; c < CCH; c++) {
        if (node < N_NODES) cp[c * CPS + node] = base + run;
        hist[t * CCH + c] = run;         // bucket-relative cursor
        run += v[c];
    }
    __syncthreads();
    for (int k = base + t; k < end; k += 256) {
        int pv = ebuf[k];
        int nd = (pv >> 17) & 255;
        unsigned src = pv & 0x1FFFF;
        int c = src / CNODES;
        int pos = atomicAdd(&hist[nd * CCH + c], 1);
        csr_src[base + pos] = (int)src;
    }
}

// ---------------- MFMA GEMM: hs(bf16) = (X @ W) * dinv[row] ----------------
template<int K, bool BF16IN>
__global__ __launch_bounds__(256) void gemm_bf16(const void* __restrict__ Xv,
                                                 const float* __restrict__ W,   // [K][64]
                                                 const float* __restrict__ dinv,
                                                 ushort* __restrict__ hs) {     // [N][64] bf16
    constexpr int KP = K + 8;
    __shared__ ushort A_lds[64][KP];
    __shared__ ushort Wt_lds[64][KP];
    int t = threadIdx.x;
    long row0 = (long)blockIdx.x * 64;

    for (int i = t; i < K * 16; i += 256) {
        float4 w4 = ((const float4*)W)[i];
        int k = i >> 4, n = (i & 15) * 4;
        Wt_lds[n + 0][k] = f2bf(w4.x);
        Wt_lds[n + 1][k] = f2bf(w4.y);
        Wt_lds[n + 2][k] = f2bf(w4.z);
        Wt_lds[n + 3][k] = f2bf(w4.w);
    }
    if (BF16IN) {
        constexpr int K2 = K / 2;
        const unsigned* X = (const unsigned*)Xv;
        for (int i = t; i < 64 * K2; i += 256) {
            int r = i / K2, c = i % K2;
            unsigned val = 0;
            long row = row0 + r;
            if (row < N_NODES) val = X[row * K2 + c];
            *(unsigned*)&A_lds[r][c * 2] = val;
        }
    } else {
        constexpr int K4 = K / 4;
        const float* X = (const float*)Xv;
        for (int i = t; i < 64 * K4; i += 256) {
            int r = i / K4, c = i % K4;
            float4 val = make_float4(0.f, 0.f, 0.f, 0.f);
            long row = row0 + r;
            if (row < N_NODES) val = ((const float4*)X)[row * K4 + c];
            int cb = c * 4;
            A_lds[r][cb + 0] = f2bf(val.x);
            A_lds[r][cb + 1] = f2bf(val.y);
            A_lds[r][cb + 2] = f2bf(val.z);
            A_lds[r][cb + 3] = f2bf(val.w);
        }
    }
    __syncthreads();

    int w = t >> 6, l = t & 63;
    int m = l & 15, quad = l >> 4;
    f32x4 acc[4];
#pragma unroll
    for (int c = 0; c < 4; c++) acc[c] = (f32x4){0.f, 0.f, 0.f, 0.f};

#pragma unroll
    for (int ch = 0; ch < K / 32; ch++) {
        short8 a = *(const short8*)&A_lds[16 * w + m][32 * ch + 8 * quad];
#pragma unroll
        for (int c = 0; c < 4; c++) {
            short8 b = *(const short8*)&Wt_lds[16 * c + m][32 * ch + 8 * quad];
            acc[c] = __builtin_amdgcn_mfma_f32_16x16x32_bf16(a, b, acc[c], 0, 0, 0);
        }
    }

#pragma unroll
    for (int r = 0; r < 4; r++) {
        long node = row0 + 16 * w + quad * 4 + r;
        if (node < N_NODES) {
            float dv = dinv[node];
#pragma unroll
            for (int c = 0; c < 4; c++)
                hs[node * 64 + 16 * c + m] = f2bf(acc[c][r] * dv);
        }
    }
}

// ------- chunk-sweep gather + fused BN/ReLU (+gemv3 if LAST) -------
// NON-cooperative: all GB blocks co-resident (~48 VGPR), start chunk 0
// together and stay phase-coherent statistically. Chunk loop is a RUNTIME
// loop (I$ control); only the NPW node loop unrolls (acc[] in VGPRs).
template<bool LAST>
__global__ __launch_bounds__(256) void gather_sweep(const int* __restrict__ csr_src,
                                                    const int* __restrict__ cp,
                                                    const ushort* __restrict__ hs,
                                                    const float* __restrict__ dinv,
                                                    const float* __restrict__ b,
                                                    const float* __restrict__ g,
                                                    const float* __restrict__ beta,
                                                    const float* __restrict__ m,
                                                    const float* __restrict__ v,
                                                    ushort* __restrict__ y,
                                                    const float* __restrict__ W3,
                                                    float* __restrict__ hs3) {
    int wave = blockIdx.x * 4 + (threadIdx.x >> 6);
    int j = threadIdx.x & 63;
    int i0 = wave * NPW;

    float acc[NPW];
#pragma unroll
    for (int nb = 0; nb < NPW; nb++) {
        int i = i0 + nb;
        acc[nb] = (i < N_NODES) ? bf2f(hs[(long)i * 64 + j]) : 0.f;  // self-loop
    }

    for (int c = 0; c < CCH; c++) {       // runtime loop: keep code small
        const int* cpc = cp + (long)c * CPS;
        const int* cpn = (c == CCH - 1) ? (cp + 1) : (cp + (long)(c + 1) * CPS);
#pragma unroll
        for (int nb = 0; nb < NPW; nb++) {
            int i = i0 + nb;
            if (i >= N_NODES) continue;
            int cs = cpc[i];
            int ce = cpn[i];
            float a = acc[nb];
            int k = cs;
            for (; k + 3 < ce; k += 4) {
                int s0 = csr_src[k], s1 = csr_src[k + 1];
                int s2 = csr_src[k + 2], s3 = csr_src[k + 3];
                float f0 = bf2f(hs[(long)s0 * 64 + j]);
                float f1 = bf2f(hs[(long)s1 * 64 + j]);
                float f2 = bf2f(hs[(long)s2 * 64 + j]);
                float f3 = bf2f(hs[(long)s3 * 64 + j]);
                a += (f0 + f1) + (f2 + f3);
            }
            for (; k < ce; k++) a += bf2f(hs[(long)csr_src[k] * 64 + j]);
            acc[nb] = a;
        }
    }

    // epilogue
    float bj = b[j], mj = m[j], bej = beta[j];
    float sc = g[j] * rsqrtf(v[j] + BN_EPS_);
    float w3 = LAST ? W3[j] : 0.f;
#pragma unroll
    for (int nb = 0; nb < NPW; nb++) {
        int i = i0 + nb;
        if (i >= N_NODES) break;
        float di = dinv[i];
        float o = fmaxf((di * acc[nb] + bj - mj) * sc + bej, 0.f);
        if (LAST) {
            float p = o * w3;
#pragma unroll
            for (int off = 32; off > 0; off >>= 1) p += __shfl_xor(p, off, 64);
            if (j == 0) hs3[i] = p * di;
        } else {
            y[(long)i * 64 + j] = f2bf(o);
        }
    }
}

// ---------------- layer-3 pull + sigmoid ----------------
__global__ __launch_bounds__(256) void gather3(const int* __restrict__ row_ptr,
                                               const int* __restrict__ csr_src,
                                               const float* __restrict__ hs3,
                                               const float* __restrict__ dinv,
                                               const float* __restrict__ b3,
                                               float* __restrict__ out, int n) {
    int i = blockIdx.x * 256 + threadIdx.x;
    if (i >= n) return;
    int beg = row_ptr[i], end = row_ptr[i + 1];
    float s0 = hs3[i], s1 = 0.f, s2 = 0.f, s3 = 0.f;
    float s4 = 0.f, s5 = 0.f, s6 = 0.f, s7 = 0.f;
    int k = beg;
    for (; k + 8 <= end; k += 8) {
        s0 += hs3[csr_src[k]];
        s1 += hs3[csr_src[k + 1]];
        s2 += hs3[csr_src[k + 2]];
        s3 += hs3[csr_src[k + 3]];
        s4 += hs3[csr_src[k + 4]];
        s5 += hs3[csr_src[k + 5]];
        s6 += hs3[csr_src[k + 6]];
        s7 += hs3[csr_src[k + 7]];
    }
    for (; k < end; k++) s0 += hs3[csr_src[k]];
    float z = dinv[i] * (((s0 + s1) + (s2 + s3)) + ((s4 + s5) + (s6 + s7))) + b3[0];
    out[i] = 1.f / (1.f + expf(-z));
}

extern "C" void kernel_launch(void* const* d_in, const int* in_sizes, int n_in,
                              void* d_out, int out_size, void* d_ws, size_t ws_size,
                              hipStream_t stream) {
    const int N = N_NODES;
    const int E = E_EDGES;

    const float* x   = (const float*)d_in[0];
    const int*   ei  = (const int*)d_in[1];   // [2, E]: row0=src, row1=dst
    const float* W1  = (const float*)d_in[2];
    const float* b1  = (const float*)d_in[3];
    const float* W2  = (const float*)d_in[4];
    const float* b2  = (const float*)d_in[5];
    const float* W3  = (const float*)d_in[6];
    const float* b3  = (const float*)d_in[7];
    const float* g1  = (const float*)d_in[8];
    const float* bt1 = (const float*)d_in[9];
    const float* m1  = (const float*)d_in[10];
    const float* v1  = (const float*)d_in[11];
    const float* g2  = (const float*)d_in[12];
    const float* bt2 = (const float*)d_in[13];
    const float* m2  = (const float*)d_in[14];
    const float* v2  = (const float*)d_in[15];
    float* out = (float*)d_out;

    // workspace layout (4-byte units)
    int*    wsi         = (int*)d_ws;
    float*  dinv        = (float*)wsi;                    // N
    float*  hs3         = (float*)(wsi + (long)N);        // N
    int*    cp          = wsi + 2L * N;                   // CCH*CPS (+cp0[N]=E)
    int*    histPB      = cp + (long)CCH * CPS;           // NBUCK*PB
    int*    bucket_tot  = histPB + NBUCK * PB;            // NBUCK (pad 400)
    int*    bucket_base = bucket_tot + 400;               // NBUCK+1 (pad 400)
    int*    csr_src     = bucket_base + 400;              // E
    ushort* hsb         = (ushort*)(csr_src + (long)E);   // N*64 bf16 = 32N ints
    ushort* yb          = (ushort*)(csr_src + (long)E + 32L * N); // N*64 bf16
    int*    ebuf        = (int*)hsb;                      // E ints, aliases hsb

    // ---- CSR build (bucketed counting sort; chunk-grouped rows) ----
    passA1_hist<<<PB, 256, 0, stream>>>(ei, histPB);
    scan_rows<<<NBUCK, 256, 0, stream>>>(histPB, bucket_tot);
    scan_totals<<<1, 512, 0, stream>>>(bucket_tot, bucket_base, cp);
    passA2_scatter<<<PB, 256, 0, stream>>>(ei, histPB, bucket_base, ebuf);
    passB_place<<<NBUCK, 256, 0, stream>>>(ebuf, bucket_base, csr_src, dinv, cp);

    // ---- layer 1 ----
    gemm_bf16<IN_DIM_, false><<<(N + 63) / 64, 256, 0, stream>>>(x, W1, dinv, hsb);
    gather_sweep<false><<<GB, 256, 0, stream>>>(csr_src, cp, hsb, dinv,
                                                b1, g1, bt1, m1, v1, yb, W3, hs3);
    // ---- layer 2 (+ fused gemv3) ----
    gemm_bf16<HID_, true><<<(N + 63) / 64, 256, 0, stream>>>(yb, W2, dinv, hsb);
    gather_sweep<true><<<GB, 256, 0, stream>>>(csr_src, cp, hsb, dinv,
                                               b2, g2, bt2, m2, v2, yb, W3, hs3);
    // ---- layer 3 ----
    gather3<<<(N + 255) / 256, 256, 0, stream>>>(cp, csr_src, hs3, dinv, b3, out, N);
}